// Round 1
// baseline (123.046 us; speedup 1.0000x reference)
//
#include <hip/hip_runtime.h>
#include <cfloat>
#include <cstdint>

#define BB   4        // batches
#define NN   8192     // points per cloud
#define NT   4        // query points per thread
#define TPB  256      // threads per block
#define QBLK (NT*TPB) // 1024 query points per block
#define NBQ  (NN/QBLK)// 8 query blocks per batch
#define MS   16       // db slices
#define MSL  (NN/MS)  // 512 db points per slice

// order-preserving float<->uint mapping (works for all finite floats)
__device__ __forceinline__ unsigned mapf(float f) {
    unsigned b = __float_as_uint(f);
    return b ^ ((unsigned)((int)b >> 31) | 0x80000000u);
}
__device__ __forceinline__ float unmapf(unsigned u) {
    unsigned b = u ^ (((u & 0x80000000u) != 0u) ? 0x80000000u : 0xFFFFFFFFu);
    return __uint_as_float(b);
}

// dir 0: query = gt cloud (dist1, min over pred points)
// dir 1: query = pred cloud (dist2, min over gt points)
__global__ __launch_bounds__(TPB) void chamfer_min_kernel(
    const float* __restrict__ pred, const float* __restrict__ gt,
    const float* __restrict__ coords, unsigned* __restrict__ ws)
{
    const int dir = blockIdx.z;
    const int b   = blockIdx.y;
    const int nb  = blockIdx.x % NBQ;   // query block index
    const int ms  = blockIdx.x / NBQ;   // db slice index

    const float* qreg = (dir == 0) ? gt   : pred;  // query offsets
    const float* dreg = (dir == 0) ? pred : gt;    // db offsets
    const size_t base = (size_t)b * 3 * NN;
    const float* qr = qreg   + base;   // component c at stride NN
    const float* dr = dreg   + base;
    const float* cc = coords + base;

    __shared__ float4 tile[MSL];       // (x, y, z, |q|^2) per db point

    // stage db slice into LDS (coalesced: component arrays contiguous in n)
    const int m0 = ms * MSL;
    for (int j = threadIdx.x; j < MSL; j += TPB) {
        int m   = m0 + j;
        float x = cc[m]        + dr[m];
        float y = cc[NN + m]   + dr[NN + m];
        float z = cc[2*NN + m] + dr[2*NN + m];
        float sq = fmaf(x, x, fmaf(y, y, z * z));
        tile[j] = make_float4(x, y, z, sq);
    }

    // per-thread query points (registers)
    float px[NT], py[NT], pz[NT], sqn[NT], mv[NT];
    const int n0 = nb * QBLK + threadIdx.x;
    #pragma unroll
    for (int k = 0; k < NT; ++k) {
        int n   = n0 + k * TPB;
        float x = cc[n]        + qr[n];
        float y = cc[NN + n]   + qr[NN + n];
        float z = cc[2*NN + n] + qr[2*NN + n];
        px[k] = x; py[k] = y; pz[k] = z;
        sqn[k] = fmaf(x, x, fmaf(y, y, z * z));
        mv[k]  = FLT_MAX;
    }
    __syncthreads();

    // main loop: 5 VALU per pair (3 fma dot, 1 fma, 1 min); sqn folded in later
    #pragma unroll 4
    for (int j = 0; j < MSL; ++j) {
        float4 q = tile[j];            // broadcast ds_read_b128, conflict-free
        #pragma unroll
        for (int k = 0; k < NT; ++k) {
            float dot = fmaf(px[k], q.x, fmaf(py[k], q.y, pz[k] * q.z));
            float v   = fmaf(dot, -2.0f, q.w);
            mv[k]     = fminf(mv[k], v);
        }
    }

    // combine across m-slices: deterministic (min is order-independent)
    unsigned* o = ws + ((size_t)dir * BB + b) * NN;
    #pragma unroll
    for (int k = 0; k < NT; ++k) {
        int n = n0 + k * TPB;
        atomicMin(&o[n], mapf(sqn[k] + mv[k]));
    }
}

__global__ __launch_bounds__(256) void chamfer_reduce_kernel(
    const unsigned* __restrict__ ws, float* __restrict__ out)
{
    __shared__ float red[256];
    float s = 0.0f;
    for (int i = threadIdx.x; i < 2 * BB * NN; i += 256)
        s += unmapf(ws[i]);
    red[threadIdx.x] = s;
    __syncthreads();
    for (int w = 128; w > 0; w >>= 1) {
        if (threadIdx.x < w) red[threadIdx.x] += red[threadIdx.x + w];
        __syncthreads();
    }
    if (threadIdx.x == 0) out[0] = red[0] / (float)BB;
}

extern "C" void kernel_launch(void* const* d_in, const int* in_sizes, int n_in,
                              void* d_out, int out_size, void* d_ws, size_t ws_size,
                              hipStream_t stream) {
    const float* pred   = (const float*)d_in[0]; // registration_pred [B,3,N]
    const float* gt     = (const float*)d_in[1]; // registration_gt   [B,3,N]
    const float* coords = (const float*)d_in[2]; // coords            [B,3,N]
    unsigned*    ws     = (unsigned*)d_ws;       // 2*B*N uints = 256 KB
    float*       out    = (float*)d_out;

    // init mins to "+infinity" in mapped-uint space (0xFFFFFFFF)
    hipMemsetAsync(d_ws, 0xFF, (size_t)2 * BB * NN * sizeof(unsigned), stream);

    dim3 grid(NBQ * MS, BB, 2);  // 128 x 4 x 2 = 1024 blocks
    chamfer_min_kernel<<<grid, TPB, 0, stream>>>(pred, gt, coords, ws);
    chamfer_reduce_kernel<<<1, 256, 0, stream>>>(ws, out);
}

// Round 2
// 58.665 us; speedup vs baseline: 2.0975x; 2.0975x over previous
//
#include <hip/hip_runtime.h>
#include <cfloat>
#include <cstdint>

#define BB   4         // batches
#define NN   8192      // points per cloud
#define NT   8         // query points per thread
#define TPB  256       // threads per block
#define QBLK (NT*TPB)  // 2048 query points per block
#define NBQ  (NN/QBLK) // 4 query blocks per batch
#define MS   16        // db slices
#define MSL  (NN/MS)   // 512 db points per slice

typedef float f32x2 __attribute__((ext_vector_type(2)));

static __device__ __forceinline__ f32x2 pk_fma(f32x2 a, f32x2 b, f32x2 c) {
#if __has_builtin(__builtin_elementwise_fma)
    return __builtin_elementwise_fma(a, b, c);
#else
    f32x2 r; r.x = fmaf(a.x, b.x, c.x); r.y = fmaf(a.y, b.y, c.y); return r;
#endif
}

// order-preserving float<->uint mapping (finite floats)
__device__ __forceinline__ unsigned mapf(float f) {
    unsigned b = __float_as_uint(f);
    return b ^ ((unsigned)((int)b >> 31) | 0x80000000u);
}
__device__ __forceinline__ float unmapf(unsigned u) {
    unsigned b = u ^ (((u & 0x80000000u) != 0u) ? 0x80000000u : 0xFFFFFFFFu);
    return __uint_as_float(b);
}

// dir 0: query = gt cloud (dist1, min over pred points)
// dir 1: query = pred cloud (dist2, min over gt points)
__global__ __launch_bounds__(TPB) void chamfer_min_kernel(
    const float* __restrict__ pred, const float* __restrict__ gt,
    const float* __restrict__ coords, unsigned* __restrict__ ws)
{
    const int dir = blockIdx.z;
    const int b   = blockIdx.y;
    const int nb  = blockIdx.x % NBQ;   // query block index
    const int ms  = blockIdx.x / NBQ;   // db slice index

    const float* qreg = (dir == 0) ? gt   : pred;  // query offsets
    const float* dreg = (dir == 0) ? pred : gt;    // db offsets
    const size_t base = (size_t)b * 3 * NN;
    const float* qr = qreg   + base;
    const float* dr = dreg   + base;
    const float* cc = coords + base;

    __shared__ float4 tile[MSL];  // (-2x, -2y, -2z, |q|^2) per db point

    const int m0 = ms * MSL;
    for (int j = threadIdx.x; j < MSL; j += TPB) {
        int m   = m0 + j;
        float x = cc[m]        + dr[m];
        float y = cc[NN + m]   + dr[NN + m];
        float z = cc[2*NN + m] + dr[2*NN + m];
        float sq = fmaf(x, x, fmaf(y, y, z * z));
        tile[j] = make_float4(-2.0f * x, -2.0f * y, -2.0f * z, sq);
    }

    float px[NT], py[NT], pz[NT], sqn[NT], mv[NT];
    const int n0 = nb * QBLK + threadIdx.x;
    #pragma unroll
    for (int k = 0; k < NT; ++k) {
        int n   = n0 + k * TPB;
        float x = cc[n]        + qr[n];
        float y = cc[NN + n]   + qr[NN + n];
        float z = cc[2*NN + n] + qr[2*NN + n];
        px[k] = x; py[k] = y; pz[k] = z;
        sqn[k] = fmaf(x, x, fmaf(y, y, z * z));
        mv[k]  = FLT_MAX;
    }
    __syncthreads();

    // 2 db points / iter: 3 pk-fma + 1 min3 per query -> ~2 VALU instr/pair
    #pragma unroll 4
    for (int j = 0; j < MSL; j += 2) {
        float4 a = tile[j];
        float4 c = tile[j + 1];
        f32x2 X = {a.x, c.x};
        f32x2 Y = {a.y, c.y};
        f32x2 Z = {a.z, c.z};
        f32x2 W = {a.w, c.w};
        #pragma unroll
        for (int k = 0; k < NT; ++k) {
            f32x2 P0 = {px[k], px[k]};
            f32x2 P1 = {py[k], py[k]};
            f32x2 P2 = {pz[k], pz[k]};
            f32x2 v  = pk_fma(P0, X, pk_fma(P1, Y, pk_fma(P2, Z, W)));
            mv[k] = fminf(fminf(mv[k], v.x), v.y);   // -> v_min3_f32
        }
    }

    unsigned* o = ws + ((size_t)dir * BB + b) * NN;
    #pragma unroll
    for (int k = 0; k < NT; ++k) {
        int n = n0 + k * TPB;
        atomicMin(&o[n], mapf(sqn[k] + mv[k]));
    }
}

// stage A: 64 blocks x 256 threads, 4 elems/thread -> 64 partials
__global__ __launch_bounds__(256) void chamfer_reduce_a(
    const unsigned* __restrict__ ws, float* __restrict__ partial)
{
    int idx = blockIdx.x * 256 + threadIdx.x;          // 16384 threads
    const uint4* p = (const uint4*)ws;
    uint4 u = p[idx];
    float s = unmapf(u.x) + unmapf(u.y) + unmapf(u.z) + unmapf(u.w);
    #pragma unroll
    for (int off = 32; off > 0; off >>= 1)
        s += __shfl_down(s, off);
    __shared__ float sm[4];
    if ((threadIdx.x & 63) == 0) sm[threadIdx.x >> 6] = s;
    __syncthreads();
    if (threadIdx.x == 0)
        partial[blockIdx.x] = (sm[0] + sm[1]) + (sm[2] + sm[3]);
}

// stage B: one wave sums 64 partials, divides by B
__global__ __launch_bounds__(64) void chamfer_reduce_b(
    const float* __restrict__ partial, float* __restrict__ out)
{
    float s = partial[threadIdx.x];
    #pragma unroll
    for (int off = 32; off > 0; off >>= 1)
        s += __shfl_down(s, off);
    if (threadIdx.x == 0) out[0] = s * (1.0f / (float)BB);
}

extern "C" void kernel_launch(void* const* d_in, const int* in_sizes, int n_in,
                              void* d_out, int out_size, void* d_ws, size_t ws_size,
                              hipStream_t stream) {
    const float* pred   = (const float*)d_in[0];
    const float* gt     = (const float*)d_in[1];
    const float* coords = (const float*)d_in[2];
    unsigned*    ws     = (unsigned*)d_ws;                 // 2*B*N uints = 256 KB
    float*       part   = (float*)((char*)d_ws + (size_t)2 * BB * NN * sizeof(unsigned));
    float*       out    = (float*)d_out;

    hipMemsetAsync(d_ws, 0xFF, (size_t)2 * BB * NN * sizeof(unsigned), stream);

    dim3 grid(NBQ * MS, BB, 2);  // 64 x 4 x 2 = 512 blocks
    chamfer_min_kernel<<<grid, TPB, 0, stream>>>(pred, gt, coords, ws);
    chamfer_reduce_a<<<64, 256, 0, stream>>>(ws, part);
    chamfer_reduce_b<<<1, 64, 0, stream>>>(part, out);
}

// Round 3
// 44.133 us; speedup vs baseline: 2.7881x; 1.3293x over previous
//
#include <hip/hip_runtime.h>
#include <cfloat>
#include <cstdint>

#define BB    4              // batches
#define NN    8192           // points per cloud
#define NT    8              // rows (gt queries) per thread
#define TPB   256            // threads per block
#define NTILE (NT*TPB)       // 2048 rows per block
#define NBQ   (NN/NTILE)     // 4 row-tiles
#define MSL   128            // pred points per slice
#define MS    (NN/MSL)       // 64 slices
#define NPAIR (MSL/2)        // 64 m-pairs == 64 lanes

// order-preserving float<->uint mapping (finite floats)
__device__ __forceinline__ unsigned mapf(float f) {
    unsigned b = __float_as_uint(f);
    return b ^ ((unsigned)((int)b >> 31) | 0x80000000u);
}
__device__ __forceinline__ float unmapf(unsigned u) {
    unsigned b = u ^ (((u & 0x80000000u) != 0u) ? 0x80000000u : 0xFFFFFFFFu);
    return __uint_as_float(b);
}

// One pass over the distance matrix: rows = gt cloud (dist1), cols = pred
// cloud (dist2). Each block: 2048 rows (regs) x 128 cols (LDS). Row-min in
// registers; col-min in per-wave LDS arrays with lane-staggered RMW.
__global__ __launch_bounds__(TPB) void chamfer_onepass_kernel(
    const float* __restrict__ pred, const float* __restrict__ gt,
    const float* __restrict__ coords, unsigned* __restrict__ ws)
{
    const int b  = blockIdx.y;
    const int nb = blockIdx.x & (NBQ - 1);
    const int ms = blockIdx.x >> 2;          // blockIdx.x / NBQ
    const size_t base = (size_t)b * 3 * NN;
    const float* gr = gt     + base;
    const float* pr = pred   + base;
    const float* cc = coords + base;

    __shared__ float4 tileE[NPAIR];          // pred point 2j   : (-2x,-2y,-2z,|q|^2)
    __shared__ float4 tileO[NPAIR];          // pred point 2j+1
    __shared__ float  colmin[4][MSL];        // per-wave col partial mins

    const int tid = threadIdx.x;

    // stage pred slice (coalesced; threads 0..127)
    if (tid < MSL) {
        int m   = ms * MSL + tid;
        float x = cc[m]        + pr[m];
        float y = cc[NN + m]   + pr[NN + m];
        float z = cc[2*NN + m] + pr[2*NN + m];
        float4 v = make_float4(-2.f*x, -2.f*y, -2.f*z, fmaf(x, x, fmaf(y, y, z*z)));
        if (tid & 1) tileO[tid >> 1] = v; else tileE[tid >> 1] = v;
    }
    for (int j = tid; j < 4 * MSL; j += TPB) (&colmin[0][0])[j] = FLT_MAX;

    // gt rows in registers
    float px[NT], py[NT], pz[NT], sqn[NT], mv[NT];
    const int n0 = nb * NTILE + tid;
    #pragma unroll
    for (int k = 0; k < NT; ++k) {
        int n   = n0 + k * TPB;
        float x = cc[n]        + gr[n];
        float y = cc[NN + n]   + gr[NN + n];
        float z = cc[2*NN + n] + gr[2*NN + n];
        px[k] = x; py[k] = y; pz[k] = z;
        sqn[k] = fmaf(x, x, fmaf(y, y, z*z));
        mv[k]  = FLT_MAX;
    }
    __syncthreads();

    const int lane = tid & 63;
    float* cm = colmin[tid >> 6];

    int jp = lane;                            // staggered start: race-free colmin RMW
    for (int i = 0; i < NPAIR; ++i) {
        float4 a = tileE[jp];
        float4 c = tileO[jp];
        float d0[NT], d1[NT];
        #pragma unroll
        for (int k = 0; k < NT; ++k) {
            d0[k] = fmaf(px[k], a.x, fmaf(py[k], a.y, fmaf(pz[k], a.z, sqn[k] + a.w)));
            d1[k] = fmaf(px[k], c.x, fmaf(py[k], c.y, fmaf(pz[k], c.z, sqn[k] + c.w)));
            mv[k] = fminf(fminf(mv[k], d0[k]), d1[k]);      // v_min3
        }
        // col partial: 8 -> 1 via min3-friendly chains
        float c0 = fminf(fminf(d0[0], d0[1]), d0[2]);
        c0 = fminf(fminf(c0, d0[3]), d0[4]);
        c0 = fminf(fminf(c0, d0[5]), d0[6]);
        c0 = fminf(c0, d0[7]);
        float c1 = fminf(fminf(d1[0], d1[1]), d1[2]);
        c1 = fminf(fminf(c1, d1[3]), d1[4]);
        c1 = fminf(fminf(c1, d1[5]), d1[6]);
        c1 = fminf(c1, d1[7]);
        // per-wave colmin RMW (distinct slot per lane each step)
        float2* slot = (float2*)&cm[2 * jp];
        float2 old = *slot;
        old.x = fminf(old.x, c0);
        old.y = fminf(old.y, c1);
        *slot = old;
        jp = (jp + 1) & (NPAIR - 1);
    }

    // dist1: row mins -> global (true squared distances; no correction needed)
    unsigned* wsrow = ws + (size_t)b * NN;
    #pragma unroll
    for (int k = 0; k < NT; ++k)
        atomicMin(&wsrow[n0 + k * TPB], mapf(mv[k]));

    __syncthreads();
    // dist2: combine 4 wave arrays, one atomic per col
    unsigned* wscol = ws + (size_t)BB * NN + (size_t)b * NN;
    if (tid < MSL) {
        float v = fminf(fminf(colmin[0][tid], colmin[1][tid]),
                        fminf(colmin[2][tid], colmin[3][tid]));
        atomicMin(&wscol[ms * MSL + tid], mapf(v));
    }
}

// stage A: 64 blocks x 256 threads, uint4 per thread -> 64 partials
__global__ __launch_bounds__(256) void chamfer_reduce_a(
    const unsigned* __restrict__ ws, float* __restrict__ partial)
{
    int idx = blockIdx.x * 256 + threadIdx.x;
    const uint4* p = (const uint4*)ws;
    uint4 u = p[idx];
    float s = (unmapf(u.x) + unmapf(u.y)) + (unmapf(u.z) + unmapf(u.w));
    #pragma unroll
    for (int off = 32; off > 0; off >>= 1)
        s += __shfl_down(s, off);
    __shared__ float sm[4];
    if ((threadIdx.x & 63) == 0) sm[threadIdx.x >> 6] = s;
    __syncthreads();
    if (threadIdx.x == 0)
        partial[blockIdx.x] = (sm[0] + sm[1]) + (sm[2] + sm[3]);
}

__global__ __launch_bounds__(64) void chamfer_reduce_b(
    const float* __restrict__ partial, float* __restrict__ out)
{
    float s = partial[threadIdx.x];
    #pragma unroll
    for (int off = 32; off > 0; off >>= 1)
        s += __shfl_down(s, off);
    if (threadIdx.x == 0) out[0] = s * (1.0f / (float)BB);
}

extern "C" void kernel_launch(void* const* d_in, const int* in_sizes, int n_in,
                              void* d_out, int out_size, void* d_ws, size_t ws_size,
                              hipStream_t stream) {
    const float* pred   = (const float*)d_in[0];
    const float* gt     = (const float*)d_in[1];
    const float* coords = (const float*)d_in[2];
    unsigned*    wsu    = (unsigned*)d_ws;     // 2*B*N uints = 256 KB
    float*       part   = (float*)((char*)d_ws + (size_t)2 * BB * NN * sizeof(unsigned));
    float*       out    = (float*)d_out;

    hipMemsetAsync(d_ws, 0xFF, (size_t)2 * BB * NN * sizeof(unsigned), stream);

    dim3 grid(NBQ * MS, BB);                   // 256 x 4 = 1024 blocks
    chamfer_onepass_kernel<<<grid, TPB, 0, stream>>>(pred, gt, coords, wsu);
    chamfer_reduce_a<<<64, 256, 0, stream>>>(wsu, part);
    chamfer_reduce_b<<<1, 64, 0, stream>>>(part, out);
}

// Round 4
// 43.325 us; speedup vs baseline: 2.8401x; 1.0187x over previous
//
#include <hip/hip_runtime.h>
#include <cfloat>
#include <cstdint>

#define BB    4              // batches
#define NN    8192           // points per cloud
#define NT    8              // rows (gt queries) per thread
#define TPB   256            // threads per block
#define NTILE (NT*TPB)       // 2048 rows per block
#define NBQ   (NN/NTILE)     // 4 row-tiles
#define MSL   64             // pred points (cols) per block
#define MS    (NN/MSL)       // 128 col slices
#define NPAIR (MSL/2)        // 32 col-pairs
#define NHW   (TPB/32)       // 8 half-waves per block

// order-preserving float<->uint mapping (finite floats)
__device__ __forceinline__ unsigned mapf(float f) {
    unsigned b = __float_as_uint(f);
    return b ^ ((unsigned)((int)b >> 31) | 0x80000000u);
}
__device__ __forceinline__ float unmapf(unsigned u) {
    unsigned b = u ^ (((u & 0x80000000u) != 0u) ? 0x80000000u : 0xFFFFFFFFu);
    return __uint_as_float(b);
}

// One pass over the distance matrix: rows = gt cloud (dist1), cols = pred
// cloud (dist2). Block: 2048 rows (regs) x 64 cols (LDS). Row-min in regs of
// d' = |q|^2 - 2 p.q (sqn added once at the end); col-min in per-half-wave
// LDS arrays, lane-staggered RMW (race-free), next-tile prefetch in regs.
__global__ __launch_bounds__(TPB) void chamfer_onepass_kernel(
    const float* __restrict__ pred, const float* __restrict__ gt,
    const float* __restrict__ coords, unsigned* __restrict__ ws)
{
    const int b  = blockIdx.y;
    const int nb = blockIdx.x & (NBQ - 1);
    const int ms = blockIdx.x >> 2;          // blockIdx.x / NBQ
    const size_t base = (size_t)b * 3 * NN;
    const float* gr = gt     + base;
    const float* pr = pred   + base;
    const float* cc = coords + base;

    __shared__ float4 tileE[NPAIR];          // pred point 2j   : (-2x,-2y,-2z,|q|^2)
    __shared__ float4 tileO[NPAIR];          // pred point 2j+1
    __shared__ float  colmin[NHW][MSL];      // per-half-wave col partial mins

    const int tid = threadIdx.x;

    // stage pred slice
    if (tid < MSL) {
        int m   = ms * MSL + tid;
        float x = cc[m]        + pr[m];
        float y = cc[NN + m]   + pr[NN + m];
        float z = cc[2*NN + m] + pr[2*NN + m];
        float4 v = make_float4(-2.f*x, -2.f*y, -2.f*z, fmaf(x, x, fmaf(y, y, z*z)));
        if (tid & 1) tileO[tid >> 1] = v; else tileE[tid >> 1] = v;
    }
    #pragma unroll
    for (int j = tid; j < NHW * MSL; j += TPB) (&colmin[0][0])[j] = FLT_MAX;

    // gt rows in registers
    float px[NT], py[NT], pz[NT], sqn[NT], mv[NT];
    const int n0 = nb * NTILE + tid;
    #pragma unroll
    for (int k = 0; k < NT; ++k) {
        int n   = n0 + k * TPB;
        float x = cc[n]        + gr[n];
        float y = cc[NN + n]   + gr[NN + n];
        float z = cc[2*NN + n] + gr[2*NN + n];
        px[k] = x; py[k] = y; pz[k] = z;
        sqn[k] = fmaf(x, x, fmaf(y, y, z*z));
        mv[k]  = FLT_MAX;   // accumulates d' = sqm - 2 dot (sqn added at end)
    }
    __syncthreads();

    const int ll = tid & 31;                 // lane within half-wave
    float* cm = colmin[tid >> 5];

    int jp = ll;
    float4 a = tileE[jp];
    float4 c = tileO[jp];
    #pragma unroll 2
    for (int i = 0; i < NPAIR; ++i) {
        const int jn = (jp + 1) & (NPAIR - 1);
        float4 an = tileE[jn];               // prefetch next pair
        float4 cn = tileO[jn];
        float d0[NT], d1[NT];
        #pragma unroll
        for (int k = 0; k < NT; ++k) {
            d0[k] = fmaf(px[k], a.x, fmaf(py[k], a.y, fmaf(pz[k], a.z, a.w)));
            d1[k] = fmaf(px[k], c.x, fmaf(py[k], c.y, fmaf(pz[k], c.z, c.w)));
            mv[k] = fminf(fminf(mv[k], d0[k]), d1[k]);      // v_min3
        }
        // col partial: min over 8 rows of (d' + sqn)
        float c0 = fminf(fminf(d0[0] + sqn[0], d0[1] + sqn[1]), d0[2] + sqn[2]);
        c0 = fminf(fminf(c0, d0[3] + sqn[3]), d0[4] + sqn[4]);
        c0 = fminf(fminf(c0, d0[5] + sqn[5]), d0[6] + sqn[6]);
        c0 = fminf(c0, d0[7] + sqn[7]);
        float c1 = fminf(fminf(d1[0] + sqn[0], d1[1] + sqn[1]), d1[2] + sqn[2]);
        c1 = fminf(fminf(c1, d1[3] + sqn[3]), d1[4] + sqn[4]);
        c1 = fminf(fminf(c1, d1[5] + sqn[5]), d1[6] + sqn[6]);
        c1 = fminf(c1, d1[7] + sqn[7]);
        // half-wave colmin RMW: distinct float2 slot per lane each step
        float2* slot = (float2*)&cm[2 * jp];
        float2 old = *slot;
        old.x = fminf(old.x, c0);
        old.y = fminf(old.y, c1);
        *slot = old;
        jp = jn; a = an; c = cn;
    }

    // dist1: row mins -> global
    unsigned* wsrow = ws + (size_t)b * NN;
    #pragma unroll
    for (int k = 0; k < NT; ++k)
        atomicMin(&wsrow[n0 + k * TPB], mapf(mv[k] + sqn[k]));

    __syncthreads();
    // dist2: combine 8 half-wave arrays, one atomic per col
    unsigned* wscol = ws + (size_t)BB * NN + (size_t)b * NN;
    if (tid < MSL) {
        float v = colmin[0][tid];
        #pragma unroll
        for (int h = 1; h < NHW; ++h) v = fminf(v, colmin[h][tid]);
        atomicMin(&wscol[ms * MSL + tid], mapf(v));
    }
}

// init mins to +inf in mapped-uint space (0xFFFFFFFF), 16384 uint4 stores
__global__ __launch_bounds__(256) void ws_init_kernel(unsigned* __restrict__ ws)
{
    ((uint4*)ws)[blockIdx.x * 256 + threadIdx.x] = make_uint4(~0u, ~0u, ~0u, ~0u);
}

// stage A: 64 blocks x 256 threads, uint4 per thread -> 64 partials
__global__ __launch_bounds__(256) void chamfer_reduce_a(
    const unsigned* __restrict__ ws, float* __restrict__ partial)
{
    int idx = blockIdx.x * 256 + threadIdx.x;
    const uint4* p = (const uint4*)ws;
    uint4 u = p[idx];
    float s = (unmapf(u.x) + unmapf(u.y)) + (unmapf(u.z) + unmapf(u.w));
    #pragma unroll
    for (int off = 32; off > 0; off >>= 1)
        s += __shfl_down(s, off);
    __shared__ float sm[4];
    if ((threadIdx.x & 63) == 0) sm[threadIdx.x >> 6] = s;
    __syncthreads();
    if (threadIdx.x == 0)
        partial[blockIdx.x] = (sm[0] + sm[1]) + (sm[2] + sm[3]);
}

__global__ __launch_bounds__(64) void chamfer_reduce_b(
    const float* __restrict__ partial, float* __restrict__ out)
{
    float s = partial[threadIdx.x];
    #pragma unroll
    for (int off = 32; off > 0; off >>= 1)
        s += __shfl_down(s, off);
    if (threadIdx.x == 0) out[0] = s * (1.0f / (float)BB);
}

extern "C" void kernel_launch(void* const* d_in, const int* in_sizes, int n_in,
                              void* d_out, int out_size, void* d_ws, size_t ws_size,
                              hipStream_t stream) {
    const float* pred   = (const float*)d_in[0];
    const float* gt     = (const float*)d_in[1];
    const float* coords = (const float*)d_in[2];
    unsigned*    wsu    = (unsigned*)d_ws;     // 2*B*N uints = 256 KB
    float*       part   = (float*)((char*)d_ws + (size_t)2 * BB * NN * sizeof(unsigned));
    float*       out    = (float*)d_out;

    ws_init_kernel<<<64, 256, 0, stream>>>(wsu);
    dim3 grid(NBQ * MS, BB);                   // 512 x 4 = 2048 blocks
    chamfer_onepass_kernel<<<grid, TPB, 0, stream>>>(pred, gt, coords, wsu);
    chamfer_reduce_a<<<64, 256, 0, stream>>>(wsu, part);
    chamfer_reduce_b<<<1, 64, 0, stream>>>(part, out);
}